// Round 15
// baseline (91.538 us; speedup 1.0000x reference)
//
#include <hip/hip_runtime.h>

#define B_ 16
#define T_ 4096
#define D_ 128
#define L_ 128
#define NC_ 32            // T_/L_
#define CH_ (B_*NC_)      // 512 chunks
#define LDP 136

typedef __attribute__((ext_vector_type(8))) short bf16x8;
typedef __attribute__((ext_vector_type(4))) float f32x4;

__device__ __forceinline__ float clampf(float x, float lo, float hi) {
    return fminf(fmaxf(x, lo), hi);
}
__device__ __forceinline__ float phi_f(float x) {   // elu(x)+1
    return x > 0.f ? x + 1.f : __expf(x);
}
__device__ __forceinline__ unsigned short bf16r(float f) {  // RNE f32->bf16
    unsigned u = __builtin_bit_cast(unsigned, f);
    u += 0x7FFFu + ((u >> 16) & 1u);
    return (unsigned short)(u >> 16);
}
__device__ __forceinline__ float fbf(unsigned short h) {
    unsigned u = ((unsigned)h) << 16; return __builtin_bit_cast(float, u);
}
__device__ __forceinline__ unsigned pack2bf(float a, float b) {
    return (unsigned)bf16r(a) | ((unsigned)bf16r(b) << 16);
}
__device__ __forceinline__ uint4 pack8(const float* f) {
    uint4 r;
    r.x = pack2bf(f[0], f[1]); r.y = pack2bf(f[2], f[3]);
    r.z = pack2bf(f[4], f[5]); r.w = pack2bf(f[6], f[7]);
    return r;
}
__device__ __forceinline__ f32x4 zero4() { f32x4 z; z[0]=0.f; z[1]=0.f; z[2]=0.f; z[3]=0.f; return z; }

// A-layout (MFMA 16x16x32 A-operand) octet index for a 128(row) x 128(k) bf16 matrix:
//   octet(row, k0): flat = (((row>>4)*4 + (k0>>5))*64 + ((k0>>3)&3)*16 + (row&15))*8
__device__ __forceinline__ int aidx(int row, int k0) {
    return (((row >> 4) * 4 + (k0 >> 5)) * 64 + ((k0 >> 3) & 3) * 16 + (row & 15)) * 8;
}

// ================= kS: phiKT row-pass + VtT gather + (q==0) cumlog/wexp =================
__global__ __launch_bounds__(256) void kS(
        const float* __restrict__ kk, const float* __restrict__ vv,
        const float* __restrict__ mask,
        const float* __restrict__ beta,
        const float* __restrict__ bb1, const float* __restrict__ bb2,
        unsigned short* __restrict__ phiKT, unsigned short* __restrict__ VtT,
        float* __restrict__ lg1, float* __restrict__ lg2, float* __restrict__ wexp) {
    int g = blockIdx.x;
    int ch = g >> 2, q = g & 3;
    int b = ch / NC_, c = ch % NC_;
    int tbase = b * T_ + c * L_;
    int tid = threadIdx.x;
    size_t cb = (size_t)ch * 16384;
    __shared__ float tot1s[2], tot2s[2];

    // ---- cumlog scan (only q==0 blocks; all threads hit the barrier) ----
    float cx1 = 0.f, cx2 = 0.f;
    int clane = tid & 63, cw = tid >> 6;
    if (q == 0 && tid < 128) {
        float b1b = clampf(1.f / (1.f + __expf(-bb1[0])), 0.01f, 0.995f);
        float b2b = clampf(1.f / (1.f + __expf(-bb2[0])), 0.01f, 0.995f);
        float be = clampf(beta[tbase + tid], 0.01f, 0.995f);
        cx1 = __logf(clampf(b1b * be, 0.01f, 0.995f));
        cx2 = __logf(clampf(b2b * be, 0.01f, 0.995f));
#pragma unroll
        for (int off = 1; off < 64; off <<= 1) {
            float y1 = __shfl_up(cx1, off);
            float y2 = __shfl_up(cx2, off);
            if (clane >= off) { cx1 += y1; cx2 += y2; }
        }
        if (clane == 63) { tot1s[cw] = cx1; tot2s[cw] = cx2; }
    }
    __syncthreads();
    if (q == 0 && tid < 128) {
        if (cw == 1) { cx1 += tot1s[0]; cx2 += tot2s[0]; }
        float tot1 = tot1s[0] + tot1s[1];
        float tot2 = tot2s[0] + tot2s[1];
        lg1[tbase + tid] = cx1;
        lg2[tbase + tid] = cx2;
        wexp[(size_t)ch * 128 + tid]                     = __expf(tot1 - cx1);
        wexp[(size_t)CH_ * 128 + (size_t)ch * 128 + tid] = __expf(tot2 - cx2);
    }

    // ---- row-pass K: octets (s, d0), s in [q*32, q*32+32) ----
#pragma unroll
    for (int p = 0; p < 2; ++p) {
        int i = p * 256 + tid;                 // 0..511
        int s = q * 32 + (i >> 4), d0 = (i & 15) * 8;
        const float* kp = &kk[(size_t)(tbase + s) * D_ + d0];
        float4 x0 = *(const float4*)kp, x1 = *(const float4*)(kp + 4);
        float m = mask[tbase + s];
        float pq[8] = {phi_f(x0.x)*m, phi_f(x0.y)*m, phi_f(x0.z)*m, phi_f(x0.w)*m,
                       phi_f(x1.x)*m, phi_f(x1.y)*m, phi_f(x1.z)*m, phi_f(x1.w)*m};
        *(uint4*)&phiKT[cb + aidx(s, d0)] = pack8(pq);
    }

    // ---- V-gather: octets (e, s0), e in [q*32, q*32+32) ----
#pragma unroll
    for (int p = 0; p < 2; ++p) {
        int i = p * 256 + tid;
        int e = q * 32 + (i & 31), s0 = (i >> 5) * 8;
        const float* vp = &vv[(size_t)(tbase + s0) * D_ + e];
        float f[8];
#pragma unroll
        for (int j = 0; j < 8; ++j)
            f[j] = vp[(size_t)j * D_];
        *(uint4*)&VtT[cb + aidx(e, s0)] = pack8(f);
    }
}

// ================= kC v4: phiKT(bf16)->LDS transpose + chunk-state GEMM + zc ==========
__global__ __launch_bounds__(512, 4) void kC(
        const unsigned short* __restrict__ phiKT,
        const unsigned short* __restrict__ VtT, const float* __restrict__ wexp,
        unsigned short* __restrict__ Cws, float* __restrict__ zc) {
    int g = blockIdx.x;                       // 1024 blocks
    int ch = ((g >> 4) << 3) | (g & 7);       // XCD pairing
    int st = (g >> 3) & 1;
    int b = ch / NC_, c = ch % NC_;
    int tid = threadIdx.x, lane = tid & 63, w = tid >> 6;   // w: 0..7 = e-tile
    int l15 = lane & 15, lg4 = lane >> 4;
    size_t cb = (size_t)ch * 16384;
    __shared__ unsigned short sKt[16384];     // 32 KB: phiK^T [d][s] in A-layout

    // ---- phiKT (linear octets, coalesced) -> sKt transposed ----
#pragma unroll
    for (int p = 0; p < 4; ++p) {
        int o = p * 512 + tid;                // 2048 octets, linear in phiKT
        uint4 pk = *(const uint4*)&phiKT[cb + (size_t)o * 8];
        int l15s = o & 15, kgrp = (o >> 4) & 3, ktile = (o >> 6) & 3, stile = o >> 8;
        int s = stile * 16 + l15s, d0 = ktile * 32 + kgrp * 8;
        unsigned short pu[8] = {
            (unsigned short)(pk.x & 0xffff), (unsigned short)(pk.x >> 16),
            (unsigned short)(pk.y & 0xffff), (unsigned short)(pk.y >> 16),
            (unsigned short)(pk.z & 0xffff), (unsigned short)(pk.z >> 16),
            (unsigned short)(pk.w & 0xffff), (unsigned short)(pk.w >> 16)};
#pragma unroll
        for (int j = 0; j < 8; ++j)
            sKt[aidx(d0 + j, s & ~7) + (s & 7)] = pu[j];
    }
    __syncthreads();

    const float* wp = &wexp[(size_t)st * CH_ * 128 + (size_t)ch * 128];

    f32x4 acc[8];
#pragma unroll
    for (int n = 0; n < 8; ++n) acc[n] = zero4();
    float zp[8] = {0.f, 0.f, 0.f, 0.f, 0.f, 0.f, 0.f, 0.f};

#pragma unroll
    for (int ks = 0; ks < 4; ++ks) {
        int koff = ks * 32 + lg4 * 8;
        float wl[8];
        {
            float4 a0 = *(const float4*)&wp[koff];
            float4 a1 = *(const float4*)&wp[koff + 4];
            wl[0]=a0.x; wl[1]=a0.y; wl[2]=a0.z; wl[3]=a0.w;
            wl[4]=a1.x; wl[5]=a1.y; wl[6]=a1.z; wl[7]=a1.w;
        }
        bf16x8 as;
        {
            bf16x8 vt = *(const bf16x8*)&VtT[cb + (size_t)(((w * 4 + ks) * 64 + lane) * 8)];
#pragma unroll
            for (int j = 0; j < 8; ++j)
                as[j] = (short)bf16r(fbf((unsigned short)vt[j]) * wl[j]);
        }
        bf16x8 bb[8];
#pragma unroll
        for (int n = 0; n < 8; ++n)
            bb[n] = *(const bf16x8*)&sKt[((n * 4 + ks) * 64 + lane) * 8];
        if (w == 0) {
#pragma unroll
            for (int n = 0; n < 8; ++n)
#pragma unroll
                for (int j = 0; j < 8; ++j)
                    zp[n] += wl[j] * fbf((unsigned short)bb[n][j]);
        }
#pragma unroll
        for (int n = 0; n < 8; ++n)
            acc[n] = __builtin_amdgcn_mfma_f32_16x16x32_bf16(as, bb[n], acc[n], 0, 0, 0);
    }

    if (w == 0) {
#pragma unroll
        for (int n = 0; n < 8; ++n) {
            float z = zp[n];
            z += __shfl_xor(z, 16); z += __shfl_xor(z, 32);
            if (lg4 == 0)
                zc[((size_t)(st * B_ + b) * NC_ + c) * D_ + n * 16 + l15] = z;
        }
    }

    __syncthreads();
#pragma unroll
    for (int n = 0; n < 8; ++n)
#pragma unroll
        for (int r = 0; r < 4; ++r) {
            int e = w * 16 + lg4 * 4 + r;
            int d = n * 16 + l15;
            sKt[aidx(e, d & ~7) + (d & 7)] = bf16r(acc[n][r]);
        }
    __syncthreads();
    unsigned short* Cp = Cws + ((size_t)(st * B_ + b) * NC_ + c) * (D_ * D_);
#pragma unroll
    for (int p = 0; p < 4; ++p) {
        int i = p * 512 + tid;
        *(uint4*)&Cp[(size_t)i * 8] = *(const uint4*)&sKt[i * 8];
    }
}

// ================= k2f: chunk-state scans =================
__global__ void k2f(unsigned short* __restrict__ Cws, float* __restrict__ zc,
                    const float* __restrict__ lg1, const float* __restrict__ lg2) {
    int g = blockIdx.x * blockDim.x + threadIdx.x;
    if (g < 131072) {
        int st = g >> 16;
        int rem = g & 65535;
        int b = rem >> 12;
        int de = (rem & 4095) * 4;
        const float* lg = st ? lg2 : lg1;
        size_t base = ((size_t)(st * B_ + b) * NC_) * (D_ * D_) + de;
        float run0 = 0.f, run1 = 0.f, run2 = 0.f, run3 = 0.f;
#pragma unroll
        for (int c = 0; c < NC_; c++) {
            float a = __expf(lg[b * T_ + c * L_ + L_ - 1]);
            uint2 val = *(uint2*)&Cws[base + (size_t)c * (D_ * D_)];
            float t0 = fbf((unsigned short)(val.x & 0xffff)), t1 = fbf((unsigned short)(val.x >> 16));
            float t2 = fbf((unsigned short)(val.y & 0xffff)), t3 = fbf((unsigned short)(val.y >> 16));
            uint2 wv; wv.x = pack2bf(run0, run1); wv.y = pack2bf(run2, run3);
            *(uint2*)&Cws[base + (size_t)c * (D_ * D_)] = wv;
            run0 = a * run0 + t0; run1 = a * run1 + t1;
            run2 = a * run2 + t2; run3 = a * run3 + t3;
        }
    } else {
        int gz = g - 131072;
        int st = gz >> 11;
        int rem = gz & 2047;
        int b = rem >> 7;
        int d = rem & 127;
        const float* lg = st ? lg2 : lg1;
        size_t base = ((size_t)(st * B_ + b) * NC_) * D_ + d;
        float run = 0.f;
#pragma unroll
        for (int c = 0; c < NC_; c++) {
            float a = __expf(lg[b * T_ + c * L_ + L_ - 1]);
            float tmp = zc[base + (size_t)c * D_];
            zc[base + (size_t)c * D_] = run;
            run = a * run + tmp;
        }
    }
}

// ================= k3 v11: phase-2 loads hoisted; phase1 t-owned, phase2 e-owned ==========
__global__ __launch_bounds__(512, 4) void k3_v11(
        const float* __restrict__ qq, const float* __restrict__ mask,
        const float* __restrict__ lg1, const float* __restrict__ lg2,
        const unsigned short* __restrict__ phiKT, const unsigned short* __restrict__ VtT,
        const unsigned short* __restrict__ Cws, const float* __restrict__ zc,
        float* __restrict__ out) {
    __shared__ unsigned short sQ[128 * LDP];       // phiQ bf16 rows [t][d]
    __shared__ unsigned short bufP[8][16 * LDP];   // P^T per t-tile (first 32KB = phiK stage)
    __shared__ float sOsc[128], sA1[128], sA2[128];
    int ch = blockIdx.x;
    int b = ch / NC_, c = ch % NC_;
    int tbase = b * T_ + c * L_;
    int tid = threadIdx.x, lane = tid & 63, w = tid >> 6;   // w: 0..7
    int l15 = lane & 15, lg4 = lane >> 4;
    size_t cb = (size_t)ch * 16384;
    unsigned short* sPK = &bufP[0][0];             // 32 KB overlay

    // ---- HOISTED phase-2 operands: issue now, consume after B3 (latency hides under phase 1)
    int m = w;
    bf16x8 vf[4], hf0[4], hf1[4];
    {
        const unsigned short* Hp0 = Cws + ((size_t)(0 * B_ + b) * NC_ + c) * (D_ * D_);
        const unsigned short* Hp1 = Cws + ((size_t)(1 * B_ + b) * NC_ + c) * (D_ * D_);
#pragma unroll
        for (int ks = 0; ks < 4; ++ks) {
            vf[ks]  = *(const bf16x8*)&VtT[cb + (size_t)(((m * 4 + ks) * 64 + lane) * 8)];
            hf0[ks] = *(const bf16x8*)&Hp0[(size_t)(((m * 4 + ks) * 64 + lane) * 8)];
            hf1[ks] = *(const bf16x8*)&Hp1[(size_t)(((m * 4 + ks) * 64 + lane) * 8)];
        }
    }

    // ---- stage phiKT -> LDS (linear copy, coalesced both sides) ----
#pragma unroll
    for (int p = 0; p < 4; ++p) {
        int i = p * 512 + tid;                     // 2048 octets
        *(uint4*)&sPK[i * 8] = *(const uint4*)&phiKT[cb + (size_t)i * 8];
    }

    // =============== PHASE 1: wave w owns t-tile w ===============
    int trow = w * 16 + l15;
    size_t gt = (size_t)(tbase + trow);
    float lg1t = lg1[gt], lg2t = lg2[gt], mt = mask[gt];
    float a1t = __expf(lg1t), a2t = __expf(lg2t);

    // phiQ B-fragments + stage into sQ
    bf16x8 qf[4];
#pragma unroll
    for (int ks = 0; ks < 4; ++ks) {
        int koff = ks * 32 + lg4 * 8;
        const float* qp = &qq[gt * D_ + koff];
        float4 x0 = *(const float4*)qp, x1 = *(const float4*)(qp + 4);
        float p0[8] = {phi_f(x0.x), phi_f(x0.y), phi_f(x0.z), phi_f(x0.w),
                       phi_f(x1.x), phi_f(x1.y), phi_f(x1.z), phi_f(x1.w)};
#pragma unroll
        for (int j = 0; j < 8; ++j) qf[ks][j] = (short)bf16r(p0[j]);
        *(uint4*)&sQ[trow * LDP + koff] = __builtin_bit_cast(uint4, qf[ks]);
    }

    // den inter-chunk dots
    const float* z1p = &zc[((size_t)(0 * B_ + b) * NC_ + c) * D_];
    const float* z2p = &zc[((size_t)(1 * B_ + b) * NC_ + c) * D_];
    float d1 = 0.f, d2 = 0.f;
#pragma unroll
    for (int ks = 0; ks < 4; ++ks) {
        int off = ks * 32 + lg4 * 8;
        float4 za = *(const float4*)(z1p + off), zb = *(const float4*)(z1p + off + 4);
        float4 zca = *(const float4*)(z2p + off), zcb = *(const float4*)(z2p + off + 4);
        float z1a[8] = {za.x, za.y, za.z, za.w, zb.x, zb.y, zb.z, zb.w};
        float z2a[8] = {zca.x, zca.y, zca.z, zca.w, zcb.x, zcb.y, zcb.z, zcb.w};
#pragma unroll
        for (int j = 0; j < 8; ++j) {
            float fq = fbf((unsigned short)qf[ks][j]);
            d1 += fq * z1a[j]; d2 += fq * z2a[j];
        }
    }
    d1 += __shfl_xor(d1, 16); d1 += __shfl_xor(d1, 32);
    d2 += __shfl_xor(d2, 16); d2 += __shfl_xor(d2, 32);

    __syncthreads();   // B1: sPK staged

    // ---- S^T from LDS phiK: statically unrolled accs (guarded) ----
    int SN = (w | 1) + 1;
    int KP = SN >> 1;
    f32x4 accs[8];
#pragma unroll
    for (int x = 0; x < 8; ++x) accs[x] = zero4();
#pragma unroll
    for (int sp = 0; sp < 4; ++sp) {
        if (sp < KP) {
            bf16x8 kf[8];
#pragma unroll
            for (int mm = 0; mm < 2; ++mm)
#pragma unroll
                for (int ks = 0; ks < 4; ++ks)
                    kf[mm * 4 + ks] = *(const bf16x8*)&sPK[((((sp * 2 + mm) * 4) + ks) * 64 + lane) * 8];
#pragma unroll
            for (int ks = 0; ks < 4; ++ks) {
                accs[sp * 2 + 0] = __builtin_amdgcn_mfma_f32_16x16x32_bf16(kf[ks],     qf[ks], accs[sp * 2 + 0], 0, 0, 0);
                accs[sp * 2 + 1] = __builtin_amdgcn_mfma_f32_16x16x32_bf16(kf[4 + ks], qf[ks], accs[sp * 2 + 1], 0, 0, 0);
            }
        }
    }
    __syncthreads();   // B2: all sPK reads done -> bufP region free

    // ---- P (decay+causal) -> bufP[w], rowsum, osc ----
    float rs = 0.f;
#pragma unroll
    for (int sp = 0; sp < 4; ++sp) {
        if (sp < KP) {
#pragma unroll
            for (int mm = 0; mm < 2; ++mm) {
                int s0 = (sp * 2 + mm) * 16 + lg4 * 4;
                float4 l1s = *(const float4*)&lg1[tbase + s0];
                float4 l2s = *(const float4*)&lg2[tbase + s0];
                float l1a[4] = {l1s.x, l1s.y, l1s.z, l1s.w};
                float l2a[4] = {l2s.x, l2s.y, l2s.z, l2s.w};
                float pv[4];
#pragma unroll
                for (int r = 0; r < 4; ++r) {
                    int s = s0 + r;
                    float p = 0.f;
                    if (s <= trow)
                        p = accs[sp * 2 + mm][r] * (__expf(lg1t - l1a[r]) + __expf(lg2t - l2a[r]));
                    pv[r] = p; rs += p;
                }
                uint2 dd; dd.x = pack2bf(pv[0], pv[1]); dd.y = pack2bf(pv[2], pv[3]);
                *(uint2*)&bufP[w][l15 * LDP + s0] = dd;
            }
        }
    }
    rs += __shfl_xor(rs, 16); rs += __shfl_xor(rs, 32);
    float osc = mt / fmaxf(a1t * d1 + a2t * d2 + rs, 1e-6f);
    if (lg4 == 0) {
        sOsc[trow] = osc;
        sA1[trow] = a1t;
        sA2[trow] = a2t;
    }
    __syncthreads();   // B3: P, sQ, sOsc/sA visible

    // =============== PHASE 2: wave w owns e-tile m = w (operands already in regs) ===============
    {
        f32x4 accO[8];
#pragma unroll
        for (int tt = 0; tt < 8; ++tt) accO[tt] = zero4();

        // QH state 0
        {
            f32x4 U[8];
#pragma unroll
            for (int tt = 0; tt < 8; ++tt) U[tt] = zero4();
#pragma unroll
            for (int ks = 0; ks < 4; ++ks) {
                int koff = ks * 32 + lg4 * 8;
#pragma unroll
                for (int tt = 0; tt < 8; ++tt) {
                    bf16x8 qb = *(const bf16x8*)&sQ[(tt * 16 + l15) * LDP + koff];
                    U[tt] = __builtin_amdgcn_mfma_f32_16x16x32_bf16(hf0[ks], qb, U[tt], 0, 0, 0);
                }
            }
#pragma unroll
            for (int tt = 0; tt < 8; ++tt) {
                float sc = sA1[tt * 16 + l15];
#pragma unroll
                for (int r = 0; r < 4; ++r) accO[tt][r] += sc * U[tt][r];
            }
        }
        // QH state 1
        {
            f32x4 U[8];
#pragma unroll
            for (int tt = 0; tt < 8; ++tt) U[tt] = zero4();
#pragma unroll
            for (int ks = 0; ks < 4; ++ks) {
                int koff = ks * 32 + lg4 * 8;
#pragma unroll
                for (int tt = 0; tt < 8; ++tt) {
                    bf16x8 qb = *(const bf16x8*)&sQ[(tt * 16 + l15) * LDP + koff];
                    U[tt] = __builtin_amdgcn_mfma_f32_16x16x32_bf16(hf1[ks], qb, U[tt], 0, 0, 0);
                }
            }
#pragma unroll
            for (int tt = 0; tt < 8; ++tt) {
                float sc = sA2[tt * 16 + l15];
#pragma unroll
                for (int r = 0; r < 4; ++r) accO[tt][r] += sc * U[tt][r];
            }
        }

        // PV: accO[tt] += Vt(m) @ P^T(tt), causal k-range
#pragma unroll
        for (int tt = 0; tt < 8; ++tt) {
            int KPt = ((tt | 1) + 1) >> 1;
            for (int ks = 0; ks < KPt; ++ks) {
                bf16x8 pf = *(const bf16x8*)&bufP[tt][l15 * LDP + ks * 32 + lg4 * 8];
                accO[tt] = __builtin_amdgcn_mfma_f32_16x16x32_bf16(vf[ks], pf, accO[tt], 0, 0, 0);
            }
        }

        // store
#pragma unroll
        for (int tt = 0; tt < 8; ++tt) {
            float oscr = sOsc[tt * 16 + l15];
            float4 o;
            o.x = accO[tt][0] * oscr; o.y = accO[tt][1] * oscr;
            o.z = accO[tt][2] * oscr; o.w = accO[tt][3] * oscr;
            *(float4*)&out[(size_t)(tbase + tt * 16 + l15) * D_ + m * 16 + lg4 * 4] = o;
        }
    }
}

extern "C" void kernel_launch(void* const* d_in, const int* in_sizes, int n_in,
                              void* d_out, int out_size, void* d_ws, size_t ws_size,
                              hipStream_t stream) {
    const float* q    = (const float*)d_in[0];
    const float* k    = (const float*)d_in[1];
    const float* v    = (const float*)d_in[2];
    const float* beta = (const float*)d_in[3];
    const float* mask = (const float*)d_in[4];
    const float* bb1  = (const float*)d_in[5];
    const float* bb2  = (const float*)d_in[6];
    float* out = (float*)d_out;

    size_t n_lg = (size_t)B_ * T_;                       // 65536
    size_t n_z  = (size_t)2 * B_ * NC_ * D_;             // 131072
    size_t n_w  = (size_t)2 * CH_ * 128;                 // 131072
    size_t n_C  = (size_t)2 * B_ * NC_ * D_ * D_;        // 16777216 bf16
    size_t n_kt = (size_t)B_ * T_ * D_;                  // 8388608 bf16
    size_t need = (2 * n_lg + n_z + n_w) * sizeof(float) + (n_C + 2 * n_kt) * sizeof(unsigned short);
    if (ws_size < need) return;

    float* lg1  = (float*)d_ws;
    float* lg2  = lg1 + n_lg;
    float* zc   = lg2 + n_lg;
    float* wexp = zc + n_z;
    unsigned short* Cws    = (unsigned short*)(wexp + n_w);
    unsigned short* phiKT  = Cws + n_C;
    unsigned short* VtT    = phiKT + n_kt;

    kS<<<4 * CH_, 256, 0, stream>>>(k, v, mask, beta, bb1, bb2, phiKT, VtT, lg1, lg2, wexp);
    kC<<<2 * CH_, 512, 0, stream>>>(phiKT, VtT, wexp, Cws, zc);
    k2f<<<528, 256, 0, stream>>>(Cws, zc, lg1, lg2);
    k3_v11<<<CH_, 512, 0, stream>>>(q, mask, lg1, lg2, phiKT, VtT, Cws, zc, out);
}

// Round 17
// 80.512 us; speedup vs baseline: 1.1369x; 1.1369x over previous
//
#include <hip/hip_runtime.h>

#define B_ 16
#define T_ 4096
#define D_ 128
#define L_ 128
#define NC_ 32            // T_/L_
#define CH_ (B_*NC_)      // 512 chunks
#define LDP 136

typedef __attribute__((ext_vector_type(8))) short bf16x8;
typedef __attribute__((ext_vector_type(4))) float f32x4;

__device__ __forceinline__ float clampf(float x, float lo, float hi) {
    return fminf(fmaxf(x, lo), hi);
}
__device__ __forceinline__ float phi_f(float x) {   // elu(x)+1
    return x > 0.f ? x + 1.f : __expf(x);
}
__device__ __forceinline__ unsigned short bf16r(float f) {  // RNE f32->bf16
    unsigned u = __builtin_bit_cast(unsigned, f);
    u += 0x7FFFu + ((u >> 16) & 1u);
    return (unsigned short)(u >> 16);
}
__device__ __forceinline__ float fbf(unsigned short h) {
    unsigned u = ((unsigned)h) << 16; return __builtin_bit_cast(float, u);
}
__device__ __forceinline__ unsigned pack2bf(float a, float b) {
    return (unsigned)bf16r(a) | ((unsigned)bf16r(b) << 16);
}
__device__ __forceinline__ uint4 pack8(const float* f) {
    uint4 r;
    r.x = pack2bf(f[0], f[1]); r.y = pack2bf(f[2], f[3]);
    r.z = pack2bf(f[4], f[5]); r.w = pack2bf(f[6], f[7]);
    return r;
}
__device__ __forceinline__ f32x4 zero4() { f32x4 z; z[0]=0.f; z[1]=0.f; z[2]=0.f; z[3]=0.f; return z; }

// A-layout (MFMA 16x16x32 A-operand) octet index for a 128(row) x 128(k) bf16 matrix:
//   octet(row, k0): flat = (((row>>4)*4 + (k0>>5))*64 + ((k0>>3)&3)*16 + (row&15))*8
__device__ __forceinline__ int aidx(int row, int k0) {
    return (((row >> 4) * 4 + (k0 >> 5)) * 64 + ((k0 >> 3) & 3) * 16 + (row & 15)) * 8;
}

// ================= kS: phiKT + phiQT row-passes + VtT gather + (q==0) cumlog/wexp ========
__global__ __launch_bounds__(256) void kS(
        const float* __restrict__ qq,
        const float* __restrict__ kk, const float* __restrict__ vv,
        const float* __restrict__ mask,
        const float* __restrict__ beta,
        const float* __restrict__ bb1, const float* __restrict__ bb2,
        unsigned short* __restrict__ phiKT, unsigned short* __restrict__ phiQT,
        unsigned short* __restrict__ VtT,
        float* __restrict__ lg1, float* __restrict__ lg2, float* __restrict__ wexp) {
    int g = blockIdx.x;
    int ch = g >> 2, q = g & 3;
    int b = ch / NC_, c = ch % NC_;
    int tbase = b * T_ + c * L_;
    int tid = threadIdx.x;
    size_t cb = (size_t)ch * 16384;
    __shared__ float tot1s[2], tot2s[2];

    // ---- cumlog scan (only q==0 blocks; all threads hit the barrier) ----
    float cx1 = 0.f, cx2 = 0.f;
    int clane = tid & 63, cw = tid >> 6;
    if (q == 0 && tid < 128) {
        float b1b = clampf(1.f / (1.f + __expf(-bb1[0])), 0.01f, 0.995f);
        float b2b = clampf(1.f / (1.f + __expf(-bb2[0])), 0.01f, 0.995f);
        float be = clampf(beta[tbase + tid], 0.01f, 0.995f);
        cx1 = __logf(clampf(b1b * be, 0.01f, 0.995f));
        cx2 = __logf(clampf(b2b * be, 0.01f, 0.995f));
#pragma unroll
        for (int off = 1; off < 64; off <<= 1) {
            float y1 = __shfl_up(cx1, off);
            float y2 = __shfl_up(cx2, off);
            if (clane >= off) { cx1 += y1; cx2 += y2; }
        }
        if (clane == 63) { tot1s[cw] = cx1; tot2s[cw] = cx2; }
    }
    __syncthreads();
    if (q == 0 && tid < 128) {
        if (cw == 1) { cx1 += tot1s[0]; cx2 += tot2s[0]; }
        float tot1 = tot1s[0] + tot1s[1];
        float tot2 = tot2s[0] + tot2s[1];
        lg1[tbase + tid] = cx1;
        lg2[tbase + tid] = cx2;
        wexp[(size_t)ch * 128 + tid]                     = __expf(tot1 - cx1);
        wexp[(size_t)CH_ * 128 + (size_t)ch * 128 + tid] = __expf(tot2 - cx2);
    }

    // ---- row-pass K -> phiKT (A-layout) ----
#pragma unroll
    for (int p = 0; p < 2; ++p) {
        int i = p * 256 + tid;                 // 0..511
        int s = q * 32 + (i >> 4), d0 = (i & 15) * 8;
        const float* kp = &kk[(size_t)(tbase + s) * D_ + d0];
        float4 x0 = *(const float4*)kp, x1 = *(const float4*)(kp + 4);
        float m = mask[tbase + s];
        float pq[8] = {phi_f(x0.x)*m, phi_f(x0.y)*m, phi_f(x0.z)*m, phi_f(x0.w)*m,
                       phi_f(x1.x)*m, phi_f(x1.y)*m, phi_f(x1.z)*m, phi_f(x1.w)*m};
        *(uint4*)&phiKT[cb + aidx(s, d0)] = pack8(pq);
    }

    // ---- row-pass Q -> phiQT (row-major bf16 [t][128], coalesced) ----
#pragma unroll
    for (int p = 0; p < 2; ++p) {
        int i = p * 256 + tid;
        int s = q * 32 + (i >> 4), d0 = (i & 15) * 8;
        const float* qp = &qq[(size_t)(tbase + s) * D_ + d0];
        float4 x0 = *(const float4*)qp, x1 = *(const float4*)(qp + 4);
        float pq[8] = {phi_f(x0.x), phi_f(x0.y), phi_f(x0.z), phi_f(x0.w),
                       phi_f(x1.x), phi_f(x1.y), phi_f(x1.z), phi_f(x1.w)};
        *(uint4*)&phiQT[cb + (size_t)(s * 128 + d0)] = pack8(pq);
    }

    // ---- V-gather: octets (e, s0), e in [q*32, q*32+32) ----
#pragma unroll
    for (int p = 0; p < 2; ++p) {
        int i = p * 256 + tid;
        int e = q * 32 + (i & 31), s0 = (i >> 5) * 8;
        const float* vp = &vv[(size_t)(tbase + s0) * D_ + e];
        float f[8];
#pragma unroll
        for (int j = 0; j < 8; ++j)
            f[j] = vp[(size_t)j * D_];
        *(uint4*)&VtT[cb + aidx(e, s0)] = pack8(f);
    }
}

// ================= kC v4: phiKT(bf16)->LDS transpose + chunk-state GEMM + zc ==========
__global__ __launch_bounds__(512, 4) void kC(
        const unsigned short* __restrict__ phiKT,
        const unsigned short* __restrict__ VtT, const float* __restrict__ wexp,
        unsigned short* __restrict__ Cws, float* __restrict__ zc) {
    int g = blockIdx.x;                       // 1024 blocks
    int ch = ((g >> 4) << 3) | (g & 7);       // XCD pairing
    int st = (g >> 3) & 1;
    int b = ch / NC_, c = ch % NC_;
    int tid = threadIdx.x, lane = tid & 63, w = tid >> 6;   // w: 0..7 = e-tile
    int l15 = lane & 15, lg4 = lane >> 4;
    size_t cb = (size_t)ch * 16384;
    __shared__ unsigned short sKt[16384];     // 32 KB: phiK^T [d][s] in A-layout

    // ---- phiKT (linear octets, coalesced) -> sKt transposed ----
#pragma unroll
    for (int p = 0; p < 4; ++p) {
        int o = p * 512 + tid;                // 2048 octets, linear in phiKT
        uint4 pk = *(const uint4*)&phiKT[cb + (size_t)o * 8];
        int l15s = o & 15, kgrp = (o >> 4) & 3, ktile = (o >> 6) & 3, stile = o >> 8;
        int s = stile * 16 + l15s, d0 = ktile * 32 + kgrp * 8;
        unsigned short pu[8] = {
            (unsigned short)(pk.x & 0xffff), (unsigned short)(pk.x >> 16),
            (unsigned short)(pk.y & 0xffff), (unsigned short)(pk.y >> 16),
            (unsigned short)(pk.z & 0xffff), (unsigned short)(pk.z >> 16),
            (unsigned short)(pk.w & 0xffff), (unsigned short)(pk.w >> 16)};
#pragma unroll
        for (int j = 0; j < 8; ++j)
            sKt[aidx(d0 + j, s & ~7) + (s & 7)] = pu[j];
    }
    __syncthreads();

    const float* wp = &wexp[(size_t)st * CH_ * 128 + (size_t)ch * 128];

    f32x4 acc[8];
#pragma unroll
    for (int n = 0; n < 8; ++n) acc[n] = zero4();
    float zp[8] = {0.f, 0.f, 0.f, 0.f, 0.f, 0.f, 0.f, 0.f};

#pragma unroll
    for (int ks = 0; ks < 4; ++ks) {
        int koff = ks * 32 + lg4 * 8;
        float wl[8];
        {
            float4 a0 = *(const float4*)&wp[koff];
            float4 a1 = *(const float4*)&wp[koff + 4];
            wl[0]=a0.x; wl[1]=a0.y; wl[2]=a0.z; wl[3]=a0.w;
            wl[4]=a1.x; wl[5]=a1.y; wl[6]=a1.z; wl[7]=a1.w;
        }
        bf16x8 as;
        {
            bf16x8 vt = *(const bf16x8*)&VtT[cb + (size_t)(((w * 4 + ks) * 64 + lane) * 8)];
#pragma unroll
            for (int j = 0; j < 8; ++j)
                as[j] = (short)bf16r(fbf((unsigned short)vt[j]) * wl[j]);
        }
        bf16x8 bb[8];
#pragma unroll
        for (int n = 0; n < 8; ++n)
            bb[n] = *(const bf16x8*)&sKt[((n * 4 + ks) * 64 + lane) * 8];
        if (w == 0) {
#pragma unroll
            for (int n = 0; n < 8; ++n)
#pragma unroll
                for (int j = 0; j < 8; ++j)
                    zp[n] += wl[j] * fbf((unsigned short)bb[n][j]);
        }
#pragma unroll
        for (int n = 0; n < 8; ++n)
            acc[n] = __builtin_amdgcn_mfma_f32_16x16x32_bf16(as, bb[n], acc[n], 0, 0, 0);
    }

    if (w == 0) {
#pragma unroll
        for (int n = 0; n < 8; ++n) {
            float z = zp[n];
            z += __shfl_xor(z, 16); z += __shfl_xor(z, 32);
            if (lg4 == 0)
                zc[((size_t)(st * B_ + b) * NC_ + c) * D_ + n * 16 + l15] = z;
        }
    }

    __syncthreads();
#pragma unroll
    for (int n = 0; n < 8; ++n)
#pragma unroll
        for (int r = 0; r < 4; ++r) {
            int e = w * 16 + lg4 * 4 + r;
            int d = n * 16 + l15;
            sKt[aidx(e, d & ~7) + (d & 7)] = bf16r(acc[n][r]);
        }
    __syncthreads();
    unsigned short* Cp = Cws + ((size_t)(st * B_ + b) * NC_ + c) * (D_ * D_);
#pragma unroll
    for (int p = 0; p < 4; ++p) {
        int i = p * 512 + tid;
        *(uint4*)&Cp[(size_t)i * 8] = *(const uint4*)&sKt[i * 8];
    }
}

// ================= k2f: chunk-state scans =================
__global__ void k2f(unsigned short* __restrict__ Cws, float* __restrict__ zc,
                    const float* __restrict__ lg1, const float* __restrict__ lg2) {
    int g = blockIdx.x * blockDim.x + threadIdx.x;
    if (g < 131072) {
        int st = g >> 16;
        int rem = g & 65535;
        int b = rem >> 12;
        int de = (rem & 4095) * 4;
        const float* lg = st ? lg2 : lg1;
        size_t base = ((size_t)(st * B_ + b) * NC_) * (D_ * D_) + de;
        float run0 = 0.f, run1 = 0.f, run2 = 0.f, run3 = 0.f;
#pragma unroll
        for (int c = 0; c < NC_; c++) {
            float a = __expf(lg[b * T_ + c * L_ + L_ - 1]);
            uint2 val = *(uint2*)&Cws[base + (size_t)c * (D_ * D_)];
            float t0 = fbf((unsigned short)(val.x & 0xffff)), t1 = fbf((unsigned short)(val.x >> 16));
            float t2 = fbf((unsigned short)(val.y & 0xffff)), t3 = fbf((unsigned short)(val.y >> 16));
            uint2 wv; wv.x = pack2bf(run0, run1); wv.y = pack2bf(run2, run3);
            *(uint2*)&Cws[base + (size_t)c * (D_ * D_)] = wv;
            run0 = a * run0 + t0; run1 = a * run1 + t1;
            run2 = a * run2 + t2; run3 = a * run3 + t3;
        }
    } else {
        int gz = g - 131072;
        int st = gz >> 11;
        int rem = gz & 2047;
        int b = rem >> 7;
        int d = rem & 127;
        const float* lg = st ? lg2 : lg1;
        size_t base = ((size_t)(st * B_ + b) * NC_) * D_ + d;
        float run = 0.f;
#pragma unroll
        for (int c = 0; c < NC_; c++) {
            float a = __expf(lg[b * T_ + c * L_ + L_ - 1]);
            float tmp = zc[base + (size_t)c * D_];
            zc[base + (size_t)c * D_] = run;
            run = a * run + tmp;
        }
    }
}

// ================= k3 v12: all-bf16 linear staging; phase1 t-owned, phase2 e-owned =======
__global__ __launch_bounds__(512, 2) void k3_v12(
        const float* __restrict__ mask,
        const float* __restrict__ lg1, const float* __restrict__ lg2,
        const unsigned short* __restrict__ phiKT, const unsigned short* __restrict__ phiQT,
        const unsigned short* __restrict__ VtT,
        const unsigned short* __restrict__ Cws, const float* __restrict__ zc,
        float* __restrict__ out) {
    __shared__ unsigned short sQ[128 * LDP];       // phiQ bf16 rows [t][d]
    __shared__ unsigned short bufP[8][16 * LDP];   // P^T per t-tile (first 32KB = phiK stage)
    __shared__ float sOsc[128], sA1[128], sA2[128];
    int ch = blockIdx.x;
    int b = ch / NC_, c = ch % NC_;
    int tbase = b * T_ + c * L_;
    int tid = threadIdx.x, lane = tid & 63, w = tid >> 6;   // w: 0..7
    int l15 = lane & 15, lg4 = lane >> 4;
    size_t cb = (size_t)ch * 16384;
    unsigned short* sPK = &bufP[0][0];             // 32 KB overlay

    // ---- stage phiKT -> sPK and phiQT -> sQ (linear copies, coalesced both sides) ----
#pragma unroll
    for (int p = 0; p < 4; ++p) {
        int i = p * 512 + tid;                     // 2048 octets
        *(uint4*)&sPK[i * 8] = *(const uint4*)&phiKT[cb + (size_t)i * 8];
        int t = i >> 4, d0 = (i & 15) * 8;
        *(uint4*)&sQ[t * LDP + d0] = *(const uint4*)&phiQT[cb + (size_t)i * 8];
    }

    // =============== PHASE 1: wave w owns t-tile w ===============
    int trow = w * 16 + l15;
    size_t gt = (size_t)(tbase + trow);
    float lg1t = lg1[gt], lg2t = lg2[gt], mt = mask[gt];
    float a1t = __expf(lg1t), a2t = __expf(lg2t);

    __syncthreads();   // B1: sPK + sQ staged

    // phiQ B-fragments from LDS
    bf16x8 qf[4];
#pragma unroll
    for (int ks = 0; ks < 4; ++ks)
        qf[ks] = *(const bf16x8*)&sQ[trow * LDP + ks * 32 + lg4 * 8];

    // den inter-chunk dots
    const float* z1p = &zc[((size_t)(0 * B_ + b) * NC_ + c) * D_];
    const float* z2p = &zc[((size_t)(1 * B_ + b) * NC_ + c) * D_];
    float d1 = 0.f, d2 = 0.f;
#pragma unroll
    for (int ks = 0; ks < 4; ++ks) {
        int off = ks * 32 + lg4 * 8;
        float4 za = *(const float4*)(z1p + off), zb = *(const float4*)(z1p + off + 4);
        float4 zca = *(const float4*)(z2p + off), zcb = *(const float4*)(z2p + off + 4);
        float z1a[8] = {za.x, za.y, za.z, za.w, zb.x, zb.y, zb.z, zb.w};
        float z2a[8] = {zca.x, zca.y, zca.z, zca.w, zcb.x, zcb.y, zcb.z, zcb.w};
#pragma unroll
        for (int j = 0; j < 8; ++j) {
            float fq = fbf((unsigned short)qf[ks][j]);
            d1 += fq * z1a[j]; d2 += fq * z2a[j];
        }
    }
    d1 += __shfl_xor(d1, 16); d1 += __shfl_xor(d1, 32);
    d2 += __shfl_xor(d2, 16); d2 += __shfl_xor(d2, 32);

    // ---- S^T from LDS phiK: statically unrolled accs (guarded) ----
    int SN = (w | 1) + 1;
    int KP = SN >> 1;
    f32x4 accs[8];
#pragma unroll
    for (int x = 0; x < 8; ++x) accs[x] = zero4();
#pragma unroll
    for (int sp = 0; sp < 4; ++sp) {
        if (sp < KP) {
            bf16x8 kf[8];
#pragma unroll
            for (int mm = 0; mm < 2; ++mm)
#pragma unroll
                for (int ks = 0; ks < 4; ++ks)
                    kf[mm * 4 + ks] = *(const bf16x8*)&sPK[((((sp * 2 + mm) * 4) + ks) * 64 + lane) * 8];
#pragma unroll
            for (int ks = 0; ks < 4; ++ks) {
                accs[sp * 2 + 0] = __builtin_amdgcn_mfma_f32_16x16x32_bf16(kf[ks],     qf[ks], accs[sp * 2 + 0], 0, 0, 0);
                accs[sp * 2 + 1] = __builtin_amdgcn_mfma_f32_16x16x32_bf16(kf[4 + ks], qf[ks], accs[sp * 2 + 1], 0, 0, 0);
            }
        }
    }
    __syncthreads();   // B2: all sPK reads done -> bufP region free

    // ---- P (decay+causal) -> bufP[w], rowsum, osc ----
    float rs = 0.f;
#pragma unroll
    for (int sp = 0; sp < 4; ++sp) {
        if (sp < KP) {
#pragma unroll
            for (int mm = 0; mm < 2; ++mm) {
                int s0 = (sp * 2 + mm) * 16 + lg4 * 4;
                float4 l1s = *(const float4*)&lg1[tbase + s0];
                float4 l2s = *(const float4*)&lg2[tbase + s0];
                float l1a[4] = {l1s.x, l1s.y, l1s.z, l1s.w};
                float l2a[4] = {l2s.x, l2s.y, l2s.z, l2s.w};
                float pv[4];
#pragma unroll
                for (int r = 0; r < 4; ++r) {
                    int s = s0 + r;
                    float p = 0.f;
                    if (s <= trow)
                        p = accs[sp * 2 + mm][r] * (__expf(lg1t - l1a[r]) + __expf(lg2t - l2a[r]));
                    pv[r] = p; rs += p;
                }
                uint2 dd; dd.x = pack2bf(pv[0], pv[1]); dd.y = pack2bf(pv[2], pv[3]);
                *(uint2*)&bufP[w][l15 * LDP + s0] = dd;
            }
        }
    }
    rs += __shfl_xor(rs, 16); rs += __shfl_xor(rs, 32);
    float osc = mt / fmaxf(a1t * d1 + a2t * d2 + rs, 1e-6f);
    if (lg4 == 0) {
        sOsc[trow] = osc;
        sA1[trow] = a1t;
        sA2[trow] = a2t;
    }
    __syncthreads();   // B3: P, sOsc/sA visible

    // =============== PHASE 2: wave w owns e-tile m = w ===============
    {
        int m = w;
        bf16x8 vf[4];
#pragma unroll
        for (int ks = 0; ks < 4; ++ks)
            vf[ks] = *(const bf16x8*)&VtT[cb + (size_t)(((m * 4 + ks) * 64 + lane) * 8)];

        f32x4 accO[8];
#pragma unroll
        for (int tt = 0; tt < 8; ++tt) accO[tt] = zero4();

        // QH: per state, U = H_st(m) x phiQ, then accO += a_st(t) * U
#pragma unroll
        for (int st = 0; st < 2; ++st) {
            const unsigned short* Hp = Cws + ((size_t)(st * B_ + b) * NC_ + c) * (D_ * D_);
            bf16x8 hf[4];
#pragma unroll
            for (int ks = 0; ks < 4; ++ks)
                hf[ks] = *(const bf16x8*)&Hp[(size_t)(((m * 4 + ks) * 64 + lane) * 8)];
            f32x4 U[8];
#pragma unroll
            for (int tt = 0; tt < 8; ++tt) U[tt] = zero4();
#pragma unroll
            for (int ks = 0; ks < 4; ++ks) {
                int koff = ks * 32 + lg4 * 8;
#pragma unroll
                for (int tt = 0; tt < 8; ++tt) {
                    bf16x8 qb = *(const bf16x8*)&sQ[(tt * 16 + l15) * LDP + koff];
                    U[tt] = __builtin_amdgcn_mfma_f32_16x16x32_bf16(hf[ks], qb, U[tt], 0, 0, 0);
                }
            }
            const float* sA = st ? sA2 : sA1;
#pragma unroll
            for (int tt = 0; tt < 8; ++tt) {
                float sc = sA[tt * 16 + l15];
#pragma unroll
                for (int r = 0; r < 4; ++r) accO[tt][r] += sc * U[tt][r];
            }
        }

        // PV: accO[tt] += Vt(m) @ P^T(tt), causal k-range
#pragma unroll
        for (int tt = 0; tt < 8; ++tt) {
            int KPt = ((tt | 1) + 1) >> 1;
            for (int ks = 0; ks < KPt; ++ks) {
                bf16x8 pf = *(const bf16x8*)&bufP[tt][l15 * LDP + ks * 32 + lg4 * 8];
                accO[tt] = __builtin_amdgcn_mfma_f32_16x16x32_bf16(vf[ks], pf, accO[tt], 0, 0, 0);
            }
        }

        // store (non-temporal via native vector type: out is a pure sink)
#pragma unroll
        for (int tt = 0; tt < 8; ++tt) {
            float oscr = sOsc[tt * 16 + l15];
            f32x4 o;
            o[0] = accO[tt][0] * oscr; o[1] = accO[tt][1] * oscr;
            o[2] = accO[tt][2] * oscr; o[3] = accO[tt][3] * oscr;
            f32x4* op = (f32x4*)&out[(size_t)(tbase + tt * 16 + l15) * D_ + m * 16 + lg4 * 4];
            __builtin_nontemporal_store(o, op);
        }
    }
}

extern "C" void kernel_launch(void* const* d_in, const int* in_sizes, int n_in,
                              void* d_out, int out_size, void* d_ws, size_t ws_size,
                              hipStream_t stream) {
    const float* q    = (const float*)d_in[0];
    const float* k    = (const float*)d_in[1];
    const float* v    = (const float*)d_in[2];
    const float* beta = (const float*)d_in[3];
    const float* mask = (const float*)d_in[4];
    const float* bb1  = (const float*)d_in[5];
    const float* bb2  = (const float*)d_in[6];
    float* out = (float*)d_out;

    size_t n_lg = (size_t)B_ * T_;                       // 65536
    size_t n_z  = (size_t)2 * B_ * NC_ * D_;             // 131072
    size_t n_w  = (size_t)2 * CH_ * 128;                 // 131072
    size_t n_C  = (size_t)2 * B_ * NC_ * D_ * D_;        // 16777216 bf16
    size_t n_kt = (size_t)B_ * T_ * D_;                  // 8388608 bf16
    size_t need = (2 * n_lg + n_z + n_w) * sizeof(float) + (n_C + 3 * n_kt) * sizeof(unsigned short);
    if (ws_size < need) return;

    float* lg1  = (float*)d_ws;
    float* lg2  = lg1 + n_lg;
    float* zc   = lg2 + n_lg;
    float* wexp = zc + n_z;
    unsigned short* Cws    = (unsigned short*)(wexp + n_w);
    unsigned short* phiKT  = Cws + n_C;
    unsigned short* phiQT  = phiKT + n_kt;
    unsigned short* VtT    = phiQT + n_kt;

    kS<<<4 * CH_, 256, 0, stream>>>(q, k, v, mask, beta, bb1, bb2, phiKT, phiQT, VtT, lg1, lg2, wexp);
    kC<<<2 * CH_, 512, 0, stream>>>(phiKT, VtT, wexp, Cws, zc);
    k2f<<<528, 256, 0, stream>>>(Cws, zc, lg1, lg2);
    k3_v12<<<CH_, 512, 0, stream>>>(mask, lg1, lg2, phiKT, phiQT, VtT, Cws, zc, out);
}

// Round 18
// 76.050 us; speedup vs baseline: 1.2037x; 1.0587x over previous
//
#include <hip/hip_runtime.h>

#define B_ 16
#define T_ 4096
#define D_ 128
#define L_ 128
#define NC_ 32            // T_/L_
#define CH_ (B_*NC_)      // 512 chunks
#define LDP 136

typedef __attribute__((ext_vector_type(8))) short bf16x8;
typedef __attribute__((ext_vector_type(4))) float f32x4;

__device__ __forceinline__ float clampf(float x, float lo, float hi) {
    return fminf(fmaxf(x, lo), hi);
}
__device__ __forceinline__ float phi_f(float x) {   // elu(x)+1
    return x > 0.f ? x + 1.f : __expf(x);
}
__device__ __forceinline__ unsigned short bf16r(float f) {  // RNE f32->bf16
    unsigned u = __builtin_bit_cast(unsigned, f);
    u += 0x7FFFu + ((u >> 16) & 1u);
    return (unsigned short)(u >> 16);
}
__device__ __forceinline__ float fbf(unsigned short h) {
    unsigned u = ((unsigned)h) << 16; return __builtin_bit_cast(float, u);
}
__device__ __forceinline__ unsigned pack2bf(float a, float b) {
    return (unsigned)bf16r(a) | ((unsigned)bf16r(b) << 16);
}
__device__ __forceinline__ uint4 pack8(const float* f) {
    uint4 r;
    r.x = pack2bf(f[0], f[1]); r.y = pack2bf(f[2], f[3]);
    r.z = pack2bf(f[4], f[5]); r.w = pack2bf(f[6], f[7]);
    return r;
}
__device__ __forceinline__ f32x4 zero4() { f32x4 z; z[0]=0.f; z[1]=0.f; z[2]=0.f; z[3]=0.f; return z; }

// A-layout (MFMA 16x16x32 A-operand) octet index for a 128(row) x 128(k) bf16 matrix:
//   octet(row, k0): flat = (((row>>4)*4 + (k0>>5))*64 + ((k0>>3)&3)*16 + (row&15))*8
__device__ __forceinline__ int aidx(int row, int k0) {
    return (((row >> 4) * 4 + (k0 >> 5)) * 64 + ((k0 >> 3) & 3) * 16 + (row & 15)) * 8;
}

// ================= kS: phiKT row-pass + VtT gather + (q==0) cumlog/wexp =================
__global__ __launch_bounds__(256) void kS(
        const float* __restrict__ kk, const float* __restrict__ vv,
        const float* __restrict__ mask,
        const float* __restrict__ beta,
        const float* __restrict__ bb1, const float* __restrict__ bb2,
        unsigned short* __restrict__ phiKT, unsigned short* __restrict__ VtT,
        float* __restrict__ lg1, float* __restrict__ lg2, float* __restrict__ wexp) {
    int g = blockIdx.x;
    int ch = g >> 2, q = g & 3;
    int b = ch / NC_, c = ch % NC_;
    int tbase = b * T_ + c * L_;
    int tid = threadIdx.x;
    size_t cb = (size_t)ch * 16384;
    __shared__ float tot1s[2], tot2s[2];

    // ---- cumlog scan (only q==0 blocks; all threads hit the barrier) ----
    float cx1 = 0.f, cx2 = 0.f;
    int clane = tid & 63, cw = tid >> 6;
    if (q == 0 && tid < 128) {
        float b1b = clampf(1.f / (1.f + __expf(-bb1[0])), 0.01f, 0.995f);
        float b2b = clampf(1.f / (1.f + __expf(-bb2[0])), 0.01f, 0.995f);
        float be = clampf(beta[tbase + tid], 0.01f, 0.995f);
        cx1 = __logf(clampf(b1b * be, 0.01f, 0.995f));
        cx2 = __logf(clampf(b2b * be, 0.01f, 0.995f));
#pragma unroll
        for (int off = 1; off < 64; off <<= 1) {
            float y1 = __shfl_up(cx1, off);
            float y2 = __shfl_up(cx2, off);
            if (clane >= off) { cx1 += y1; cx2 += y2; }
        }
        if (clane == 63) { tot1s[cw] = cx1; tot2s[cw] = cx2; }
    }
    __syncthreads();
    if (q == 0 && tid < 128) {
        if (cw == 1) { cx1 += tot1s[0]; cx2 += tot2s[0]; }
        float tot1 = tot1s[0] + tot1s[1];
        float tot2 = tot2s[0] + tot2s[1];
        lg1[tbase + tid] = cx1;
        lg2[tbase + tid] = cx2;
        wexp[(size_t)ch * 128 + tid]                     = __expf(tot1 - cx1);
        wexp[(size_t)CH_ * 128 + (size_t)ch * 128 + tid] = __expf(tot2 - cx2);
    }

    // ---- row-pass K -> phiKT (A-layout) ----
#pragma unroll
    for (int p = 0; p < 2; ++p) {
        int i = p * 256 + tid;                 // 0..511
        int s = q * 32 + (i >> 4), d0 = (i & 15) * 8;
        const float* kp = &kk[(size_t)(tbase + s) * D_ + d0];
        float4 x0 = *(const float4*)kp, x1 = *(const float4*)(kp + 4);
        float m = mask[tbase + s];
        float pq[8] = {phi_f(x0.x)*m, phi_f(x0.y)*m, phi_f(x0.z)*m, phi_f(x0.w)*m,
                       phi_f(x1.x)*m, phi_f(x1.y)*m, phi_f(x1.z)*m, phi_f(x1.w)*m};
        *(uint4*)&phiKT[cb + aidx(s, d0)] = pack8(pq);
    }

    // ---- V-gather: octets (e, s0), e in [q*32, q*32+32) ----
#pragma unroll
    for (int p = 0; p < 2; ++p) {
        int i = p * 256 + tid;
        int e = q * 32 + (i & 31), s0 = (i >> 5) * 8;
        const float* vp = &vv[(size_t)(tbase + s0) * D_ + e];
        float f[8];
#pragma unroll
        for (int j = 0; j < 8; ++j)
            f[j] = vp[(size_t)j * D_];
        *(uint4*)&VtT[cb + aidx(e, s0)] = pack8(f);
    }
}

// ================= kC v4: phiKT(bf16)->LDS transpose + chunk-state GEMM + zc ==========
__global__ __launch_bounds__(512, 4) void kC(
        const unsigned short* __restrict__ phiKT,
        const unsigned short* __restrict__ VtT, const float* __restrict__ wexp,
        unsigned short* __restrict__ Cws, float* __restrict__ zc) {
    int g = blockIdx.x;                       // 1024 blocks
    int ch = ((g >> 4) << 3) | (g & 7);       // XCD pairing
    int st = (g >> 3) & 1;
    int b = ch / NC_, c = ch % NC_;
    int tid = threadIdx.x, lane = tid & 63, w = tid >> 6;   // w: 0..7 = e-tile
    int l15 = lane & 15, lg4 = lane >> 4;
    size_t cb = (size_t)ch * 16384;
    __shared__ unsigned short sKt[16384];     // 32 KB: phiK^T [d][s] in A-layout

    // ---- phiKT (linear octets, coalesced) -> sKt transposed ----
#pragma unroll
    for (int p = 0; p < 4; ++p) {
        int o = p * 512 + tid;                // 2048 octets, linear in phiKT
        uint4 pk = *(const uint4*)&phiKT[cb + (size_t)o * 8];
        int l15s = o & 15, kgrp = (o >> 4) & 3, ktile = (o >> 6) & 3, stile = o >> 8;
        int s = stile * 16 + l15s, d0 = ktile * 32 + kgrp * 8;
        unsigned short pu[8] = {
            (unsigned short)(pk.x & 0xffff), (unsigned short)(pk.x >> 16),
            (unsigned short)(pk.y & 0xffff), (unsigned short)(pk.y >> 16),
            (unsigned short)(pk.z & 0xffff), (unsigned short)(pk.z >> 16),
            (unsigned short)(pk.w & 0xffff), (unsigned short)(pk.w >> 16)};
#pragma unroll
        for (int j = 0; j < 8; ++j)
            sKt[aidx(d0 + j, s & ~7) + (s & 7)] = pu[j];
    }
    __syncthreads();

    const float* wp = &wexp[(size_t)st * CH_ * 128 + (size_t)ch * 128];

    f32x4 acc[8];
#pragma unroll
    for (int n = 0; n < 8; ++n) acc[n] = zero4();
    float zp[8] = {0.f, 0.f, 0.f, 0.f, 0.f, 0.f, 0.f, 0.f};

#pragma unroll
    for (int ks = 0; ks < 4; ++ks) {
        int koff = ks * 32 + lg4 * 8;
        float wl[8];
        {
            float4 a0 = *(const float4*)&wp[koff];
            float4 a1 = *(const float4*)&wp[koff + 4];
            wl[0]=a0.x; wl[1]=a0.y; wl[2]=a0.z; wl[3]=a0.w;
            wl[4]=a1.x; wl[5]=a1.y; wl[6]=a1.z; wl[7]=a1.w;
        }
        bf16x8 as;
        {
            bf16x8 vt = *(const bf16x8*)&VtT[cb + (size_t)(((w * 4 + ks) * 64 + lane) * 8)];
#pragma unroll
            for (int j = 0; j < 8; ++j)
                as[j] = (short)bf16r(fbf((unsigned short)vt[j]) * wl[j]);
        }
        bf16x8 bb[8];
#pragma unroll
        for (int n = 0; n < 8; ++n)
            bb[n] = *(const bf16x8*)&sKt[((n * 4 + ks) * 64 + lane) * 8];
        if (w == 0) {
#pragma unroll
            for (int n = 0; n < 8; ++n)
#pragma unroll
                for (int j = 0; j < 8; ++j)
                    zp[n] += wl[j] * fbf((unsigned short)bb[n][j]);
        }
#pragma unroll
        for (int n = 0; n < 8; ++n)
            acc[n] = __builtin_amdgcn_mfma_f32_16x16x32_bf16(as, bb[n], acc[n], 0, 0, 0);
    }

    if (w == 0) {
#pragma unroll
        for (int n = 0; n < 8; ++n) {
            float z = zp[n];
            z += __shfl_xor(z, 16); z += __shfl_xor(z, 32);
            if (lg4 == 0)
                zc[((size_t)(st * B_ + b) * NC_ + c) * D_ + n * 16 + l15] = z;
        }
    }

    __syncthreads();
#pragma unroll
    for (int n = 0; n < 8; ++n)
#pragma unroll
        for (int r = 0; r < 4; ++r) {
            int e = w * 16 + lg4 * 4 + r;
            int d = n * 16 + l15;
            sKt[aidx(e, d & ~7) + (d & 7)] = bf16r(acc[n][r]);
        }
    __syncthreads();
    unsigned short* Cp = Cws + ((size_t)(st * B_ + b) * NC_ + c) * (D_ * D_);
#pragma unroll
    for (int p = 0; p < 4; ++p) {
        int i = p * 512 + tid;
        *(uint4*)&Cp[(size_t)i * 8] = *(const uint4*)&sKt[i * 8];
    }
}

// ================= k2f: chunk-state scans =================
__global__ void k2f(unsigned short* __restrict__ Cws, float* __restrict__ zc,
                    const float* __restrict__ lg1, const float* __restrict__ lg2) {
    int g = blockIdx.x * blockDim.x + threadIdx.x;
    if (g < 131072) {
        int st = g >> 16;
        int rem = g & 65535;
        int b = rem >> 12;
        int de = (rem & 4095) * 4;
        const float* lg = st ? lg2 : lg1;
        size_t base = ((size_t)(st * B_ + b) * NC_) * (D_ * D_) + de;
        float run0 = 0.f, run1 = 0.f, run2 = 0.f, run3 = 0.f;
#pragma unroll
        for (int c = 0; c < NC_; c++) {
            float a = __expf(lg[b * T_ + c * L_ + L_ - 1]);
            uint2 val = *(uint2*)&Cws[base + (size_t)c * (D_ * D_)];
            float t0 = fbf((unsigned short)(val.x & 0xffff)), t1 = fbf((unsigned short)(val.x >> 16));
            float t2 = fbf((unsigned short)(val.y & 0xffff)), t3 = fbf((unsigned short)(val.y >> 16));
            uint2 wv; wv.x = pack2bf(run0, run1); wv.y = pack2bf(run2, run3);
            *(uint2*)&Cws[base + (size_t)c * (D_ * D_)] = wv;
            run0 = a * run0 + t0; run1 = a * run1 + t1;
            run2 = a * run2 + t2; run3 = a * run3 + t3;
        }
    } else {
        int gz = g - 131072;
        int st = gz >> 11;
        int rem = gz & 2047;
        int b = rem >> 7;
        int d = rem & 127;
        const float* lg = st ? lg2 : lg1;
        size_t base = ((size_t)(st * B_ + b) * NC_) * D_ + d;
        float run = 0.f;
#pragma unroll
        for (int c = 0; c < NC_; c++) {
            float a = __expf(lg[b * T_ + c * L_ + L_ - 1]);
            float tmp = zc[base + (size_t)c * D_];
            zc[base + (size_t)c * D_] = run;
            run = a * run + tmp;
        }
    }
}

// ================= k3 v13: q staged directly (coalesced); phase1 t-owned, phase2 e-owned ==
__global__ __launch_bounds__(512, 2) void k3_v13(
        const float* __restrict__ qq, const float* __restrict__ mask,
        const float* __restrict__ lg1, const float* __restrict__ lg2,
        const unsigned short* __restrict__ phiKT, const unsigned short* __restrict__ VtT,
        const unsigned short* __restrict__ Cws, const float* __restrict__ zc,
        float* __restrict__ out) {
    __shared__ unsigned short sQ[128 * LDP];       // phiQ bf16 rows [t][d]
    __shared__ unsigned short bufP[8][16 * LDP];   // P^T per t-tile (first 32KB = phiK stage)
    __shared__ float sOsc[128], sA1[128], sA2[128];
    int ch = blockIdx.x;
    int b = ch / NC_, c = ch % NC_;
    int tbase = b * T_ + c * L_;
    int tid = threadIdx.x, lane = tid & 63, w = tid >> 6;   // w: 0..7
    int l15 = lane & 15, lg4 = lane >> 4;
    size_t cb = (size_t)ch * 16384;
    unsigned short* sPK = &bufP[0][0];             // 32 KB overlay

    // ---- stage phiKT -> sPK (linear copy) and phiQ from q (coalesced row-major + phi) ----
#pragma unroll
    for (int p = 0; p < 4; ++p) {
        int i = p * 512 + tid;                     // 2048 octets
        *(uint4*)&sPK[i * 8] = *(const uint4*)&phiKT[cb + (size_t)i * 8];
    }
#pragma unroll
    for (int p = 0; p < 8; ++p) {
        int i = p * 512 + tid;                     // 4096 quads: t = i>>5, d4 = (i&31)*4
        int t = i >> 5, d4 = (i & 31) * 4;
        float4 x = *(const float4*)&qq[(size_t)(tbase + t) * D_ + d4];
        uint2 dd;
        dd.x = pack2bf(phi_f(x.x), phi_f(x.y));
        dd.y = pack2bf(phi_f(x.z), phi_f(x.w));
        *(uint2*)&sQ[t * LDP + d4] = dd;
    }

    // =============== PHASE 1: wave w owns t-tile w ===============
    int trow = w * 16 + l15;
    size_t gt = (size_t)(tbase + trow);
    float lg1t = lg1[gt], lg2t = lg2[gt], mt = mask[gt];
    float a1t = __expf(lg1t), a2t = __expf(lg2t);

    __syncthreads();   // B1: sPK + sQ staged

    // phiQ B-fragments from LDS
    bf16x8 qf[4];
#pragma unroll
    for (int ks = 0; ks < 4; ++ks)
        qf[ks] = *(const bf16x8*)&sQ[trow * LDP + ks * 32 + lg4 * 8];

    // den inter-chunk dots
    const float* z1p = &zc[((size_t)(0 * B_ + b) * NC_ + c) * D_];
    const float* z2p = &zc[((size_t)(1 * B_ + b) * NC_ + c) * D_];
    float d1 = 0.f, d2 = 0.f;
#pragma unroll
    for (int ks = 0; ks < 4; ++ks) {
        int off = ks * 32 + lg4 * 8;
        float4 za = *(const float4*)(z1p + off), zb = *(const float4*)(z1p + off + 4);
        float4 zca = *(const float4*)(z2p + off), zcb = *(const float4*)(z2p + off + 4);
        float z1a[8] = {za.x, za.y, za.z, za.w, zb.x, zb.y, zb.z, zb.w};
        float z2a[8] = {zca.x, zca.y, zca.z, zca.w, zcb.x, zcb.y, zcb.z, zcb.w};
#pragma unroll
        for (int j = 0; j < 8; ++j) {
            float fq = fbf((unsigned short)qf[ks][j]);
            d1 += fq * z1a[j]; d2 += fq * z2a[j];
        }
    }
    d1 += __shfl_xor(d1, 16); d1 += __shfl_xor(d1, 32);
    d2 += __shfl_xor(d2, 16); d2 += __shfl_xor(d2, 32);

    // ---- S^T from LDS phiK: statically unrolled accs (guarded) ----
    int SN = (w | 1) + 1;
    int KP = SN >> 1;
    f32x4 accs[8];
#pragma unroll
    for (int x = 0; x < 8; ++x) accs[x] = zero4();
#pragma unroll
    for (int sp = 0; sp < 4; ++sp) {
        if (sp < KP) {
            bf16x8 kf[8];
#pragma unroll
            for (int mm = 0; mm < 2; ++mm)
#pragma unroll
                for (int ks = 0; ks < 4; ++ks)
                    kf[mm * 4 + ks] = *(const bf16x8*)&sPK[((((sp * 2 + mm) * 4) + ks) * 64 + lane) * 8];
#pragma unroll
            for (int ks = 0; ks < 4; ++ks) {
                accs[sp * 2 + 0] = __builtin_amdgcn_mfma_f32_16x16x32_bf16(kf[ks],     qf[ks], accs[sp * 2 + 0], 0, 0, 0);
                accs[sp * 2 + 1] = __builtin_amdgcn_mfma_f32_16x16x32_bf16(kf[4 + ks], qf[ks], accs[sp * 2 + 1], 0, 0, 0);
            }
        }
    }
    __syncthreads();   // B2: all sPK reads done -> bufP region free

    // ---- P (decay+causal) -> bufP[w], rowsum, osc ----
    float rs = 0.f;
#pragma unroll
    for (int sp = 0; sp < 4; ++sp) {
        if (sp < KP) {
#pragma unroll
            for (int mm = 0; mm < 2; ++mm) {
                int s0 = (sp * 2 + mm) * 16 + lg4 * 4;
                float4 l1s = *(const float4*)&lg1[tbase + s0];
                float4 l2s = *(const float4*)&lg2[tbase + s0];
                float l1a[4] = {l1s.x, l1s.y, l1s.z, l1s.w};
                float l2a[4] = {l2s.x, l2s.y, l2s.z, l2s.w};
                float pv[4];
#pragma unroll
                for (int r = 0; r < 4; ++r) {
                    int s = s0 + r;
                    float p = 0.f;
                    if (s <= trow)
                        p = accs[sp * 2 + mm][r] * (__expf(lg1t - l1a[r]) + __expf(lg2t - l2a[r]));
                    pv[r] = p; rs += p;
                }
                uint2 dd; dd.x = pack2bf(pv[0], pv[1]); dd.y = pack2bf(pv[2], pv[3]);
                *(uint2*)&bufP[w][l15 * LDP + s0] = dd;
            }
        }
    }
    rs += __shfl_xor(rs, 16); rs += __shfl_xor(rs, 32);
    float osc = mt / fmaxf(a1t * d1 + a2t * d2 + rs, 1e-6f);
    if (lg4 == 0) {
        sOsc[trow] = osc;
        sA1[trow] = a1t;
        sA2[trow] = a2t;
    }
    __syncthreads();   // B3: P, sOsc/sA visible

    // =============== PHASE 2: wave w owns e-tile m = w ===============
    {
        int m = w;
        bf16x8 vf[4];
#pragma unroll
        for (int ks = 0; ks < 4; ++ks)
            vf[ks] = *(const bf16x8*)&VtT[cb + (size_t)(((m * 4 + ks) * 64 + lane) * 8)];

        f32x4 accO[8];
#pragma unroll
        for (int tt = 0; tt < 8; ++tt) accO[tt] = zero4();

        // QH: per state, U = H_st(m) x phiQ, then accO += a_st(t) * U
#pragma unroll
        for (int st = 0; st < 2; ++st) {
            const unsigned short* Hp = Cws + ((size_t)(st * B_ + b) * NC_ + c) * (D_ * D_);
            bf16x8 hf[4];
#pragma unroll
            for (int ks = 0; ks < 4; ++ks)
                hf[ks] = *(const bf16x8*)&Hp[(size_t)(((m * 4 + ks) * 64 + lane) * 8)];
            f32x4 U[8];
#pragma unroll
            for (int tt = 0; tt < 8; ++tt) U[tt] = zero4();
#pragma unroll
            for (int ks = 0; ks < 4; ++ks) {
                int koff = ks * 32 + lg4 * 8;
#pragma unroll
                for (int tt = 0; tt < 8; ++tt) {
                    bf16x8 qb = *(const bf16x8*)&sQ[(tt * 16 + l15) * LDP + koff];
                    U[tt] = __builtin_amdgcn_mfma_f32_16x16x32_bf16(hf[ks], qb, U[tt], 0, 0, 0);
                }
            }
            const float* sA = st ? sA2 : sA1;
#pragma unroll
            for (int tt = 0; tt < 8; ++tt) {
                float sc = sA[tt * 16 + l15];
#pragma unroll
                for (int r = 0; r < 4; ++r) accO[tt][r] += sc * U[tt][r];
            }
        }

        // PV: accO[tt] += Vt(m) @ P^T(tt), causal k-range
#pragma unroll
        for (int tt = 0; tt < 8; ++tt) {
            int KPt = ((tt | 1) + 1) >> 1;
            for (int ks = 0; ks < KPt; ++ks) {
                bf16x8 pf = *(const bf16x8*)&bufP[tt][l15 * LDP + ks * 32 + lg4 * 8];
                accO[tt] = __builtin_amdgcn_mfma_f32_16x16x32_bf16(vf[ks], pf, accO[tt], 0, 0, 0);
            }
        }

        // store (non-temporal via native vector type: out is a pure sink)
#pragma unroll
        for (int tt = 0; tt < 8; ++tt) {
            float oscr = sOsc[tt * 16 + l15];
            f32x4 o;
            o[0] = accO[tt][0] * oscr; o[1] = accO[tt][1] * oscr;
            o[2] = accO[tt][2] * oscr; o[3] = accO[tt][3] * oscr;
            f32x4* op = (f32x4*)&out[(size_t)(tbase + tt * 16 + l15) * D_ + m * 16 + lg4 * 4];
            __builtin_nontemporal_store(o, op);
        }
    }
}

extern "C" void kernel_launch(void* const* d_in, const int* in_sizes, int n_in,
                              void* d_out, int out_size, void* d_ws, size_t ws_size,
                              hipStream_t stream) {
    const float* q    = (const float*)d_in[0];
    const float* k    = (const float*)d_in[1];
    const float* v    = (const float*)d_in[2];
    const float* beta = (const float*)d_in[3];
    const float* mask = (const float*)d_in[4];
    const float* bb1  = (const float*)d_in[5];
    const float* bb2  = (const float*)d_in[6];
    float* out = (float*)d_out;

    size_t n_lg = (size_t)B_ * T_;                       // 65536
    size_t n_z  = (size_t)2 * B_ * NC_ * D_;             // 131072
    size_t n_w  = (size_t)2 * CH_ * 128;                 // 131072
    size_t n_C  = (size_t)2 * B_ * NC_ * D_ * D_;        // 16777216 bf16
    size_t n_kt = (size_t)B_ * T_ * D_;                  // 8388608 bf16
    size_t need = (2 * n_lg + n_z + n_w) * sizeof(float) + (n_C + 2 * n_kt) * sizeof(unsigned short);
    if (ws_size < need) return;

    float* lg1  = (float*)d_ws;
    float* lg2  = lg1 + n_lg;
    float* zc   = lg2 + n_lg;
    float* wexp = zc + n_z;
    unsigned short* Cws    = (unsigned short*)(wexp + n_w);
    unsigned short* phiKT  = Cws + n_C;
    unsigned short* VtT    = phiKT + n_kt;

    kS<<<4 * CH_, 256, 0, stream>>>(k, v, mask, beta, bb1, bb2, phiKT, VtT, lg1, lg2, wexp);
    kC<<<2 * CH_, 512, 0, stream>>>(phiKT, VtT, wexp, Cws, zc);
    k2f<<<528, 256, 0, stream>>>(Cws, zc, lg1, lg2);
    k3_v13<<<CH_, 512, 0, stream>>>(q, mask, lg1, lg2, phiKT, VtT, Cws, zc, out);
}

// Round 19
// 74.265 us; speedup vs baseline: 1.2326x; 1.0240x over previous
//
#include <hip/hip_runtime.h>

#define B_ 16
#define T_ 4096
#define D_ 128
#define L_ 128
#define NC_ 32            // T_/L_
#define CH_ (B_*NC_)      // 512 chunks
#define LDP 136

typedef __attribute__((ext_vector_type(8))) short bf16x8;
typedef __attribute__((ext_vector_type(4))) float f32x4;

__device__ __forceinline__ float clampf(float x, float lo, float hi) {
    return fminf(fmaxf(x, lo), hi);
}
__device__ __forceinline__ float phi_f(float x) {   // elu(x)+1
    return x > 0.f ? x + 1.f : __expf(x);
}
__device__ __forceinline__ unsigned short bf16r(float f) {  // RNE f32->bf16
    unsigned u = __builtin_bit_cast(unsigned, f);
    u += 0x7FFFu + ((u >> 16) & 1u);
    return (unsigned short)(u >> 16);
}
__device__ __forceinline__ float fbf(unsigned short h) {
    unsigned u = ((unsigned)h) << 16; return __builtin_bit_cast(float, u);
}
__device__ __forceinline__ unsigned pack2bf(float a, float b) {
    return (unsigned)bf16r(a) | ((unsigned)bf16r(b) << 16);
}
__device__ __forceinline__ uint4 pack8(const float* f) {
    uint4 r;
    r.x = pack2bf(f[0], f[1]); r.y = pack2bf(f[2], f[3]);
    r.z = pack2bf(f[4], f[5]); r.w = pack2bf(f[6], f[7]);
    return r;
}
__device__ __forceinline__ f32x4 zero4() { f32x4 z; z[0]=0.f; z[1]=0.f; z[2]=0.f; z[3]=0.f; return z; }

// A-layout (MFMA 16x16x32 A-operand) octet index for a 128(row) x 128(k) bf16 matrix:
//   octet(row, k0): flat = (((row>>4)*4 + (k0>>5))*64 + ((k0>>3)&3)*16 + (row&15))*8
__device__ __forceinline__ int aidx(int row, int k0) {
    return (((row >> 4) * 4 + (k0 >> 5)) * 64 + ((k0 >> 3) & 3) * 16 + (row & 15)) * 8;
}

// ========== kSC: cumlog + staging (k,v -> LDS) + phiKT/VtT emit + both-state GEMM ==========
__global__ __launch_bounds__(1024, 4) void kSC(
        const float* __restrict__ beta,
        const float* __restrict__ bb1, const float* __restrict__ bb2,
        const float* __restrict__ kk, const float* __restrict__ vv,
        const float* __restrict__ mask,
        float* __restrict__ lg1, float* __restrict__ lg2,
        unsigned short* __restrict__ phiKT, unsigned short* __restrict__ VtT,
        unsigned short* __restrict__ Cws, float* __restrict__ zc) {
    int ch = blockIdx.x;
    int b = ch / NC_, c = ch % NC_;
    int tbase = b * T_ + c * L_;
    int tid = threadIdx.x, lane = tid & 63, w = tid >> 6;   // w: 0..15
    int l15 = lane & 15, lg4 = lane >> 4;
    size_t cb = (size_t)ch * 16384;

    __shared__ unsigned short sKt[16384];   // phiK^T [d][s] A-layout (32 KB)
    __shared__ unsigned short sVt[16384];   // V^T [e][s] A-layout (32 KB)
    __shared__ float wL[2][128];
    __shared__ float tot1s[2], tot2s[2];

    // ---- cumlog scan (tid<128) ----
    float cx1 = 0.f, cx2 = 0.f;
    if (tid < 128) {
        int cl = tid & 63, cw = tid >> 6;
        float b1b = clampf(1.f / (1.f + __expf(-bb1[0])), 0.01f, 0.995f);
        float b2b = clampf(1.f / (1.f + __expf(-bb2[0])), 0.01f, 0.995f);
        float be = clampf(beta[tbase + tid], 0.01f, 0.995f);
        cx1 = __logf(clampf(b1b * be, 0.01f, 0.995f));
        cx2 = __logf(clampf(b2b * be, 0.01f, 0.995f));
#pragma unroll
        for (int off = 1; off < 64; off <<= 1) {
            float y1 = __shfl_up(cx1, off);
            float y2 = __shfl_up(cx2, off);
            if (cl >= off) { cx1 += y1; cx2 += y2; }
        }
        if (cl == 63) { tot1s[cw] = cx1; tot2s[cw] = cx2; }
    }
    __syncthreads();   // B1
    if (tid < 128) {
        if (tid >= 64) { cx1 += tot1s[0]; cx2 += tot2s[0]; }
        float tot1 = tot1s[0] + tot1s[1];
        float tot2 = tot2s[0] + tot2s[1];
        lg1[tbase + tid] = cx1;
        lg2[tbase + tid] = cx2;
        wL[0][tid] = __expf(tot1 - cx1);
        wL[1][tid] = __expf(tot2 - cx2);
    }

    // ---- gather k -> sKt (phi*mask, A-layout), 2 octets/thread ----
#pragma unroll
    for (int p = 0; p < 2; ++p) {
        int i = p * 1024 + tid;                // 2048 octets
        int d = i & 127, s0 = (i >> 7) * 8;
        const float* kp = &kk[(size_t)(tbase + s0) * D_ + d];
        const float* mp = &mask[tbase + s0];
        float f[8];
#pragma unroll
        for (int j = 0; j < 8; ++j)
            f[j] = phi_f(kp[(size_t)j * D_]) * mp[j];
        *(uint4*)&sKt[aidx(d, s0)] = pack8(f);
    }
    // ---- gather v -> sVt ----
#pragma unroll
    for (int p = 0; p < 2; ++p) {
        int i = p * 1024 + tid;
        int e = i & 127, s0 = (i >> 7) * 8;
        const float* vp = &vv[(size_t)(tbase + s0) * D_ + e];
        float f[8];
#pragma unroll
        for (int j = 0; j < 8; ++j)
            f[j] = vp[(size_t)j * D_];
        *(uint4*)&sVt[aidx(e, s0)] = pack8(f);
    }
    // ---- row-pass k -> phiKT emit (k is L2-hot from the gather) ----
#pragma unroll
    for (int p = 0; p < 2; ++p) {
        int i = p * 1024 + tid;                // 2048 octets
        int s = i >> 4, d0 = (i & 15) * 8;
        const float* kp = &kk[(size_t)(tbase + s) * D_ + d0];
        float4 x0 = *(const float4*)kp, x1 = *(const float4*)(kp + 4);
        float m = mask[tbase + s];
        float pq[8] = {phi_f(x0.x)*m, phi_f(x0.y)*m, phi_f(x0.z)*m, phi_f(x0.w)*m,
                       phi_f(x1.x)*m, phi_f(x1.y)*m, phi_f(x1.z)*m, phi_f(x1.w)*m};
        *(uint4*)&phiKT[cb + aidx(s, d0)] = pack8(pq);
    }
    __syncthreads();   // B2: wL, sKt, sVt ready

    // ---- emit VtT (linear copy from sVt) ----
#pragma unroll
    for (int p = 0; p < 2; ++p) {
        int o = p * 1024 + tid;
        *(uint4*)&VtT[cb + (size_t)o * 8] = *(const uint4*)&sVt[o * 8];
    }

    // ---- both-state chunk GEMM: wave w = (st = w>>3, e-tile m = w&7) ----
    int st = w >> 3, m = w & 7;
    const float* wp = &wL[st][0];
    f32x4 acc[8];
#pragma unroll
    for (int n = 0; n < 8; ++n) acc[n] = zero4();
    float zp[8] = {0.f, 0.f, 0.f, 0.f, 0.f, 0.f, 0.f, 0.f};

#pragma unroll
    for (int ks = 0; ks < 4; ++ks) {
        int koff = ks * 32 + lg4 * 8;
        float wl[8];
#pragma unroll
        for (int j = 0; j < 8; ++j) wl[j] = wp[koff + j];
        bf16x8 as;
        {
            bf16x8 vt = *(const bf16x8*)&sVt[((m * 4 + ks) * 64 + lane) * 8];
#pragma unroll
            for (int j = 0; j < 8; ++j)
                as[j] = (short)bf16r(fbf((unsigned short)vt[j]) * wl[j]);
        }
        bf16x8 bb[8];
#pragma unroll
        for (int n = 0; n < 8; ++n)
            bb[n] = *(const bf16x8*)&sKt[((n * 4 + ks) * 64 + lane) * 8];
        if (m == 0) {
#pragma unroll
            for (int n = 0; n < 8; ++n)
#pragma unroll
                for (int j = 0; j < 8; ++j)
                    zp[n] += wl[j] * fbf((unsigned short)bb[n][j]);
        }
#pragma unroll
        for (int n = 0; n < 8; ++n)
            acc[n] = __builtin_amdgcn_mfma_f32_16x16x32_bf16(as, bb[n], acc[n], 0, 0, 0);
    }

    // zc store (waves with m==0; one per state)
    if (m == 0) {
#pragma unroll
        for (int n = 0; n < 8; ++n) {
            float z = zp[n];
            z += __shfl_xor(z, 16); z += __shfl_xor(z, 32);
            if (lg4 == 0)
                zc[((size_t)(st * B_ + b) * NC_ + c) * D_ + n * 16 + l15] = z;
        }
    }

    __syncthreads();   // B3: all sKt/sVt reads (GEMM + VtT emit) done
    // ---- scatter acc into LDS (st0 -> sKt, st1 -> sVt), A-layout ----
    {
        unsigned short* dst = st ? sVt : sKt;
#pragma unroll
        for (int n = 0; n < 8; ++n)
#pragma unroll
            for (int r = 0; r < 4; ++r) {
                int e = m * 16 + lg4 * 4 + r;
                int d = n * 16 + l15;
                dst[aidx(e, d & ~7) + (d & 7)] = bf16r(acc[n][r]);
            }
    }
    __syncthreads();   // B4
    // ---- coalesced Cws emit (both states) ----
    unsigned short* Cp0 = Cws + ((size_t)(0 * B_ + b) * NC_ + c) * (D_ * D_);
    unsigned short* Cp1 = Cws + ((size_t)(1 * B_ + b) * NC_ + c) * (D_ * D_);
#pragma unroll
    for (int p = 0; p < 2; ++p) {
        int o = p * 1024 + tid;
        *(uint4*)&Cp0[(size_t)o * 8] = *(const uint4*)&sKt[o * 8];
        *(uint4*)&Cp1[(size_t)o * 8] = *(const uint4*)&sVt[o * 8];
    }
}

// ================= k2f: chunk-state scans =================
__global__ void k2f(unsigned short* __restrict__ Cws, float* __restrict__ zc,
                    const float* __restrict__ lg1, const float* __restrict__ lg2) {
    int g = blockIdx.x * blockDim.x + threadIdx.x;
    if (g < 131072) {
        int st = g >> 16;
        int rem = g & 65535;
        int b = rem >> 12;
        int de = (rem & 4095) * 4;
        const float* lg = st ? lg2 : lg1;
        size_t base = ((size_t)(st * B_ + b) * NC_) * (D_ * D_) + de;
        float run0 = 0.f, run1 = 0.f, run2 = 0.f, run3 = 0.f;
#pragma unroll
        for (int c = 0; c < NC_; c++) {
            float a = __expf(lg[b * T_ + c * L_ + L_ - 1]);
            uint2 val = *(uint2*)&Cws[base + (size_t)c * (D_ * D_)];
            float t0 = fbf((unsigned short)(val.x & 0xffff)), t1 = fbf((unsigned short)(val.x >> 16));
            float t2 = fbf((unsigned short)(val.y & 0xffff)), t3 = fbf((unsigned short)(val.y >> 16));
            uint2 wv; wv.x = pack2bf(run0, run1); wv.y = pack2bf(run2, run3);
            *(uint2*)&Cws[base + (size_t)c * (D_ * D_)] = wv;
            run0 = a * run0 + t0; run1 = a * run1 + t1;
            run2 = a * run2 + t2; run3 = a * run3 + t3;
        }
    } else {
        int gz = g - 131072;
        int st = gz >> 11;
        int rem = gz & 2047;
        int b = rem >> 7;
        int d = rem & 127;
        const float* lg = st ? lg2 : lg1;
        size_t base = ((size_t)(st * B_ + b) * NC_) * D_ + d;
        float run = 0.f;
#pragma unroll
        for (int c = 0; c < NC_; c++) {
            float a = __expf(lg[b * T_ + c * L_ + L_ - 1]);
            float tmp = zc[base + (size_t)c * D_];
            zc[base + (size_t)c * D_] = run;
            run = a * run + tmp;
        }
    }
}

// ================= k3 v13: q staged directly (coalesced); phase1 t-owned, phase2 e-owned ==
__global__ __launch_bounds__(512, 2) void k3_v13(
        const float* __restrict__ qq, const float* __restrict__ mask,
        const float* __restrict__ lg1, const float* __restrict__ lg2,
        const unsigned short* __restrict__ phiKT, const unsigned short* __restrict__ VtT,
        const unsigned short* __restrict__ Cws, const float* __restrict__ zc,
        float* __restrict__ out) {
    __shared__ unsigned short sQ[128 * LDP];       // phiQ bf16 rows [t][d]
    __shared__ unsigned short bufP[8][16 * LDP];   // P^T per t-tile (first 32KB = phiK stage)
    __shared__ float sOsc[128], sA1[128], sA2[128];
    int ch = blockIdx.x;
    int b = ch / NC_, c = ch % NC_;
    int tbase = b * T_ + c * L_;
    int tid = threadIdx.x, lane = tid & 63, w = tid >> 6;   // w: 0..7
    int l15 = lane & 15, lg4 = lane >> 4;
    size_t cb = (size_t)ch * 16384;
    unsigned short* sPK = &bufP[0][0];             // 32 KB overlay

    // ---- stage phiKT -> sPK (linear copy) and phiQ from q (coalesced row-major + phi) ----
#pragma unroll
    for (int p = 0; p < 4; ++p) {
        int i = p * 512 + tid;                     // 2048 octets
        *(uint4*)&sPK[i * 8] = *(const uint4*)&phiKT[cb + (size_t)i * 8];
    }
#pragma unroll
    for (int p = 0; p < 8; ++p) {
        int i = p * 512 + tid;                     // 4096 quads: t = i>>5, d4 = (i&31)*4
        int t = i >> 5, d4 = (i & 31) * 4;
        float4 x = *(const float4*)&qq[(size_t)(tbase + t) * D_ + d4];
        uint2 dd;
        dd.x = pack2bf(phi_f(x.x), phi_f(x.y));
        dd.y = pack2bf(phi_f(x.z), phi_f(x.w));
        *(uint2*)&sQ[t * LDP + d4] = dd;
    }

    // =============== PHASE 1: wave w owns t-tile w ===============
    int trow = w * 16 + l15;
    size_t gt = (size_t)(tbase + trow);
    float lg1t = lg1[gt], lg2t = lg2[gt], mt = mask[gt];
    float a1t = __expf(lg1t), a2t = __expf(lg2t);

    __syncthreads();   // B1: sPK + sQ staged

    // phiQ B-fragments from LDS
    bf16x8 qf[4];
#pragma unroll
    for (int ks = 0; ks < 4; ++ks)
        qf[ks] = *(const bf16x8*)&sQ[trow * LDP + ks * 32 + lg4 * 8];

    // den inter-chunk dots
    const float* z1p = &zc[((size_t)(0 * B_ + b) * NC_ + c) * D_];
    const float* z2p = &zc[((size_t)(1 * B_ + b) * NC_ + c) * D_];
    float d1 = 0.f, d2 = 0.f;
#pragma unroll
    for (int ks = 0; ks < 4; ++ks) {
        int off = ks * 32 + lg4 * 8;
        float4 za = *(const float4*)(z1p + off), zb = *(const float4*)(z1p + off + 4);
        float4 zca = *(const float4*)(z2p + off), zcb = *(const float4*)(z2p + off + 4);
        float z1a[8] = {za.x, za.y, za.z, za.w, zb.x, zb.y, zb.z, zb.w};
        float z2a[8] = {zca.x, zca.y, zca.z, zca.w, zcb.x, zcb.y, zcb.z, zcb.w};
#pragma unroll
        for (int j = 0; j < 8; ++j) {
            float fq = fbf((unsigned short)qf[ks][j]);
            d1 += fq * z1a[j]; d2 += fq * z2a[j];
        }
    }
    d1 += __shfl_xor(d1, 16); d1 += __shfl_xor(d1, 32);
    d2 += __shfl_xor(d2, 16); d2 += __shfl_xor(d2, 32);

    // ---- S^T from LDS phiK: statically unrolled accs (guarded) ----
    int SN = (w | 1) + 1;
    int KP = SN >> 1;
    f32x4 accs[8];
#pragma unroll
    for (int x = 0; x < 8; ++x) accs[x] = zero4();
#pragma unroll
    for (int sp = 0; sp < 4; ++sp) {
        if (sp < KP) {
            bf16x8 kf[8];
#pragma unroll
            for (int mm = 0; mm < 2; ++mm)
#pragma unroll
                for (int ks = 0; ks < 4; ++ks)
                    kf[mm * 4 + ks] = *(const bf16x8*)&sPK[((((sp * 2 + mm) * 4) + ks) * 64 + lane) * 8];
#pragma unroll
            for (int ks = 0; ks < 4; ++ks) {
                accs[sp * 2 + 0] = __builtin_amdgcn_mfma_f32_16x16x32_bf16(kf[ks],     qf[ks], accs[sp * 2 + 0], 0, 0, 0);
                accs[sp * 2 + 1] = __builtin_amdgcn_mfma_f32_16x16x32_bf16(kf[4 + ks], qf[ks], accs[sp * 2 + 1], 0, 0, 0);
            }
        }
    }
    __syncthreads();   // B2: all sPK reads done -> bufP region free

    // ---- P (decay+causal) -> bufP[w], rowsum, osc ----
    float rs = 0.f;
#pragma unroll
    for (int sp = 0; sp < 4; ++sp) {
        if (sp < KP) {
#pragma unroll
            for (int mm = 0; mm < 2; ++mm) {
                int s0 = (sp * 2 + mm) * 16 + lg4 * 4;
                float4 l1s = *(const float4*)&lg1[tbase + s0];
                float4 l2s = *(const float4*)&lg2[tbase + s0];
                float l1a[4] = {l1s.x, l1s.y, l1s.z, l1s.w};
                float l2a[4] = {l2s.x, l2s.y, l2s.z, l2s.w};
                float pv[4];
#pragma unroll
                for (int r = 0; r < 4; ++r) {
                    int s = s0 + r;
                    float p = 0.f;
                    if (s <= trow)
                        p = accs[sp * 2 + mm][r] * (__expf(lg1t - l1a[r]) + __expf(lg2t - l2a[r]));
                    pv[r] = p; rs += p;
                }
                uint2 dd; dd.x = pack2bf(pv[0], pv[1]); dd.y = pack2bf(pv[2], pv[3]);
                *(uint2*)&bufP[w][l15 * LDP + s0] = dd;
            }
        }
    }
    rs += __shfl_xor(rs, 16); rs += __shfl_xor(rs, 32);
    float osc = mt / fmaxf(a1t * d1 + a2t * d2 + rs, 1e-6f);
    if (lg4 == 0) {
        sOsc[trow] = osc;
        sA1[trow] = a1t;
        sA2[trow] = a2t;
    }
    __syncthreads();   // B3: P, sOsc/sA visible

    // =============== PHASE 2: wave w owns e-tile m = w ===============
    {
        int m = w;
        bf16x8 vf[4];
#pragma unroll
        for (int ks = 0; ks < 4; ++ks)
            vf[ks] = *(const bf16x8*)&VtT[cb + (size_t)(((m * 4 + ks) * 64 + lane) * 8)];

        f32x4 accO[8];
#pragma unroll
        for (int tt = 0; tt < 8; ++tt) accO[tt] = zero4();

        // QH: per state, U = H_st(m) x phiQ, then accO += a_st(t) * U
#pragma unroll
        for (int st = 0; st < 2; ++st) {
            const unsigned short* Hp = Cws + ((size_t)(st * B_ + b) * NC_ + c) * (D_ * D_);
            bf16x8 hf[4];
#pragma unroll
            for (int ks = 0; ks < 4; ++ks)
                hf[ks] = *(const bf16x8*)&Hp[(size_t)(((m * 4 + ks) * 64 + lane) * 8)];
            f32x4 U[8];
#pragma unroll
            for (int tt = 0; tt < 8; ++tt) U[tt] = zero4();
#pragma unroll
            for (int ks = 0; ks < 4; ++ks) {
                int koff = ks * 32 + lg4 * 8;
#pragma unroll
                for (int tt = 0; tt < 8; ++tt) {
                    bf16x8 qb = *(const bf16x8*)&sQ[(tt * 16 + l15) * LDP + koff];
                    U[tt] = __builtin_amdgcn_mfma_f32_16x16x32_bf16(hf[ks], qb, U[tt], 0, 0, 0);
                }
            }
            const float* sA = st ? sA2 : sA1;
#pragma unroll
            for (int tt = 0; tt < 8; ++tt) {
                float sc = sA[tt * 16 + l15];
#pragma unroll
                for (int r = 0; r < 4; ++r) accO[tt][r] += sc * U[tt][r];
            }
        }

        // PV: accO[tt] += Vt(m) @ P^T(tt), causal k-range
#pragma unroll
        for (int tt = 0; tt < 8; ++tt) {
            int KPt = ((tt | 1) + 1) >> 1;
            for (int ks = 0; ks < KPt; ++ks) {
                bf16x8 pf = *(const bf16x8*)&bufP[tt][l15 * LDP + ks * 32 + lg4 * 8];
                accO[tt] = __builtin_amdgcn_mfma_f32_16x16x32_bf16(vf[ks], pf, accO[tt], 0, 0, 0);
            }
        }

        // store (non-temporal via native vector type: out is a pure sink)
#pragma unroll
        for (int tt = 0; tt < 8; ++tt) {
            float oscr = sOsc[tt * 16 + l15];
            f32x4 o;
            o[0] = accO[tt][0] * oscr; o[1] = accO[tt][1] * oscr;
            o[2] = accO[tt][2] * oscr; o[3] = accO[tt][3] * oscr;
            f32x4* op = (f32x4*)&out[(size_t)(tbase + tt * 16 + l15) * D_ + m * 16 + lg4 * 4];
            __builtin_nontemporal_store(o, op);
        }
    }
}

extern "C" void kernel_launch(void* const* d_in, const int* in_sizes, int n_in,
                              void* d_out, int out_size, void* d_ws, size_t ws_size,
                              hipStream_t stream) {
    const float* q    = (const float*)d_in[0];
    const float* k    = (const float*)d_in[1];
    const float* v    = (const float*)d_in[2];
    const float* beta = (const float*)d_in[3];
    const float* mask = (const float*)d_in[4];
    const float* bb1  = (const float*)d_in[5];
    const float* bb2  = (const float*)d_in[6];
    float* out = (float*)d_out;

    size_t n_lg = (size_t)B_ * T_;                       // 65536
    size_t n_z  = (size_t)2 * B_ * NC_ * D_;             // 131072
    size_t n_C  = (size_t)2 * B_ * NC_ * D_ * D_;        // 16777216 bf16
    size_t n_kt = (size_t)B_ * T_ * D_;                  // 8388608 bf16
    size_t need = (2 * n_lg + n_z) * sizeof(float) + (n_C + 2 * n_kt) * sizeof(unsigned short);
    if (ws_size < need) return;

    float* lg1  = (float*)d_ws;
    float* lg2  = lg1 + n_lg;
    float* zc   = lg2 + n_lg;
    unsigned short* Cws    = (unsigned short*)(zc + n_z);
    unsigned short* phiKT  = Cws + n_C;
    unsigned short* VtT    = phiKT + n_kt;

    kSC<<<CH_, 1024, 0, stream>>>(beta, bb1, bb2, k, v, mask, lg1, lg2, phiKT, VtT, Cws, zc);
    k2f<<<528, 256, 0, stream>>>(Cws, zc, lg1, lg2);
    k3_v13<<<CH_, 512, 0, stream>>>(q, mask, lg1, lg2, phiKT, VtT, Cws, zc, out);
}